// Round 7
// baseline (1262.089 us; speedup 1.0000x reference)
//
#include <hip/hip_runtime.h>
#include <math.h>

#define D 128
#define NEG_SLOPE 0.2f
#define REG_LAMBDA 1e-4f
#define NORM_EPS 1e-12f

#define RPB 256          // rows per coarse bucket
#define RPB_SHIFT 8
#define MAXB 1024        // max coarse buckets (N <= 262144)
#define CHUNK 4096       // edges per bscatter block
#define TCSH 14          // 16384 cols per col-tile (for within-row edge ordering)
#define KEYMAX 4096      // 256 rows * Tc ; Tc<=16 -> N <= 262144

#define XPAD 264         // padded LDS row stride in bf16 elems (256 + 8)

using bf16x8 = __attribute__((ext_vector_type(8))) short;
using f32x4  = __attribute__((ext_vector_type(4))) float;
using f32x2  = __attribute__((ext_vector_type(2))) float;

__device__ __forceinline__ float wave_red(float v){
  #pragma unroll
  for (int o = 32; o > 0; o >>= 1) v += __shfl_xor(v, o, 64);
  return v;
}

__device__ __forceinline__ unsigned short f2bf(float f){
  unsigned int u = __float_as_uint(f);
  unsigned int r = (u + 0x7fffu + ((u >> 16) & 1u)) >> 16;  // RNE
  return (unsigned short)r;
}
__device__ __forceinline__ float bf_lo(unsigned int x){ return __uint_as_float(x << 16); }
__device__ __forceinline__ float bf_hi(unsigned int x){ return __uint_as_float(x & 0xffff0000u); }

// fp32 pair -> (bf16 pair packed in uint, fp8-e4m3 pair packed in ushort)
__global__ __launch_bounds__(256) void toq_kernel(const float* __restrict__ src, unsigned int* __restrict__ dstb,
                                                  unsigned short* __restrict__ dst8, int npairs){
  int i = blockIdx.x*256 + threadIdx.x;
  if (i >= npairs) return;
  float2 v = ((const float2*)src)[i];
  dstb[i] = (unsigned int)f2bf(v.x) | ((unsigned int)f2bf(v.y) << 16);
  int p = __builtin_amdgcn_cvt_pk_fp8_f32(v.x, v.y, 0, false);
  dst8[i] = (unsigned short)(p & 0xffff);
}

// W_gcn/W_bi (fp32 row-major) -> per-layer MFMA B-fragment order bf16.
__global__ __launch_bounds__(256) void wconv_kernel(const float* __restrict__ Wg, const float* __restrict__ Wb,
                                                    unsigned short* __restrict__ Wf, int L){
  int idx = blockIdx.x*256 + threadIdx.x;
  int total = L * 256 * D;
  if (idx >= total) return;
  int l = idx >> 15;
  int rem = idx & 32767;
  int k = rem >> 7;
  int n = rem & 127;
  float v = (k < 128) ? Wg[((size_t)l*128 + k)*D + n] : Wb[((size_t)l*128 + (k-128))*D + n];
  int ks = k >> 5, quad = (k >> 3) & 3, j = k & 7;
  int t = n >> 4, ln = (quad << 4) | (n & 15);
  Wf[(size_t)l*32768 + (((ks*8 + t)*64 + ln)*8 + j)] = f2bf(v);
}

// K1: coarse bucket histogram, LDS-aggregated
__global__ __launch_bounds__(256) void bhist_kernel(const int* __restrict__ erow, int* __restrict__ bcnt, int nnz, int nbk){
  __shared__ int h[MAXB];
  for (int i = threadIdx.x; i < nbk; i += 256) h[i] = 0;
  __syncthreads();
  int stride = gridDim.x * 256;
  for (int e = blockIdx.x*256 + threadIdx.x; e < nnz; e += stride)
    atomicAdd(&h[erow[e] >> RPB_SHIFT], 1);
  __syncthreads();
  for (int i = threadIdx.x; i < nbk; i += 256){
    int c = h[i];
    if (c) atomicAdd(&bcnt[i], c);
  }
}

// K2: exclusive scan of bucket counts (single block)
__global__ __launch_bounds__(1024) void bscan_kernel(const int* __restrict__ bcnt, int* __restrict__ bbase,
                                                     int* __restrict__ bcur, int* __restrict__ rowptr,
                                                     int nbk, int nnz, int n){
  __shared__ int tmp[1024];
  int t = threadIdx.x;
  int v = (t < nbk) ? bcnt[t] : 0;
  tmp[t] = v; __syncthreads();
  #pragma unroll
  for (int off = 1; off < 1024; off <<= 1){
    int a = (t >= off) ? tmp[t-off] : 0; __syncthreads();
    tmp[t] += a; __syncthreads();
  }
  if (t < nbk){ int b = tmp[t] - v; bbase[t] = b; bcur[t] = b; }
  if (t == 0){ bbase[nbk] = nnz; rowptr[n] = nnz; }
}

// K3: coarse scatter. Block sorts a CHUNK of edges by bucket in LDS, reserves
// global ranges, writes coalesced runs. ebuf.x = col | (row_low8 << 20).
__global__ __launch_bounds__(256) void bscatter_kernel(const int* __restrict__ erow, const int* __restrict__ ecol,
                                                       const float* __restrict__ eval, int* __restrict__ bcur,
                                                       int2* __restrict__ ebuf, int nnz, int nbk){
  __shared__ int2 ls[CHUNK];
  __shared__ int gdst[CHUNK];
  __shared__ int h[MAXB];
  __shared__ int hx[MAXB];
  __shared__ int tmp[256];
  int tid = threadIdx.x;
  int base = blockIdx.x * CHUNK;
  int cn = min(CHUNK, nnz - base);
  for (int i = tid; i < nbk; i += 256) h[i] = 0;
  __syncthreads();
  for (int i = tid; i < cn; i += 256)
    atomicAdd(&h[erow[base+i] >> RPB_SHIFT], 1);
  __syncthreads();
  int b0 = tid*4;
  int c0=0,c1=0,c2=0,c3=0;
  if (b0 < nbk){
    c0 = h[b0];
    if (b0+1 < nbk) c1 = h[b0+1];
    if (b0+2 < nbk) c2 = h[b0+2];
    if (b0+3 < nbk) c3 = h[b0+3];
  }
  int tsum = c0+c1+c2+c3;
  tmp[tid] = tsum; __syncthreads();
  #pragma unroll
  for (int off = 1; off < 256; off <<= 1){
    int a = (tid >= off) ? tmp[tid-off] : 0; __syncthreads();
    tmp[tid] += a; __syncthreads();
  }
  int tbase = tmp[tid] - tsum;
  if (b0 < nbk){
    hx[b0] = tbase;
    if (b0+1 < nbk) hx[b0+1] = tbase + c0;
    if (b0+2 < nbk) hx[b0+2] = tbase + c0 + c1;
    if (b0+3 < nbk) hx[b0+3] = tbase + c0 + c1 + c2;
  }
  __syncthreads();
  for (int i = tid; i < nbk; i += 256){
    int c = h[i];
    if (c > 0){
      int gb = atomicAdd(&bcur[i], c);
      h[i] = gb - hx[i];
    }
  }
  __syncthreads();
  for (int i = tid; i < cn; i += 256){
    int r = erow[base+i];
    int b = r >> RPB_SHIFT;
    int x = ecol[base+i] | ((r & (RPB-1)) << 20);
    int lpos = atomicAdd(&hx[b], 1);
    ls[lpos] = make_int2(x, __float_as_int(eval[base+i]));
    gdst[lpos] = h[b] + lpos;
  }
  __syncthreads();
  for (int i = tid; i < cn; i += 256)
    ebuf[gdst[i]] = ls[i];
}

// K4: one block per coarse bucket. Counting sort by key = (row_low8, col-tile)
// -> rowptr + final CSR (edges within a row ordered by col-tile).
// ep.x = byte offset into fp8 table (col * 128).
__global__ __launch_bounds__(256) void fscatter_kernel(const int2* __restrict__ ebuf, const int* __restrict__ bbase,
                                                       int2* __restrict__ ep, int* __restrict__ rowptr,
                                                       int Tc, int n){
  __shared__ int h[KEYMAX];
  __shared__ int tsum[256];
  int b = blockIdx.x;
  int tid = threadIdx.x;
  int s = bbase[b], e = bbase[b+1];
  int row0 = b << RPB_SHIFT;
  int nk = 256 * Tc;
  for (int i = tid; i < nk; i += 256) h[i] = 0;
  __syncthreads();
  for (int i = s + tid; i < e; i += 256){
    int x = ebuf[i].x;
    int key = ((x >> 20) & 255) * Tc + ((x & 0xFFFFF) >> TCSH);
    atomicAdd(&h[key], 1);
  }
  __syncthreads();
  // exclusive scan: thread tid owns keys of row tid (segment of Tc)
  int my0 = tid * Tc;
  int run = 0;
  for (int j = 0; j < Tc; j++){
    int c = h[my0 + j]; h[my0 + j] = run; run += c;
  }
  tsum[tid] = run; __syncthreads();
  #pragma unroll
  for (int off = 1; off < 256; off <<= 1){
    int a = (tid >= off) ? tsum[tid-off] : 0; __syncthreads();
    tsum[tid] += a; __syncthreads();
  }
  int bt = tsum[tid] - run;
  for (int j = 0; j < Tc; j++) h[my0 + j] += bt;
  __syncthreads();
  if (row0 + tid < n) rowptr[row0 + tid] = s + h[my0];
  __syncthreads();
  for (int i = s + tid; i < e; i += 256){
    int2 E = ebuf[i];
    int x = E.x;
    int col = x & 0xFFFFF;
    int key = ((x >> 20) & 255) * Tc + (col >> TCSH);
    int p = atomicAdd(&h[key], 1);
    ep[s + p] = make_int2(col << 7, E.y);   // byte offset
  }
}

// sideb[r] = bf16( sum_e val_e * ego_fp8[off_e] ); one wave per row.
// Depth-16 batches everywhere: the remainder batch clamps indices to the last
// edge (same line -> L1 hit, no extra FETCH) and zeroes the val, so every
// gather issues at full memory-level parallelism (no serial tail).
__global__ __launch_bounds__(256) void spmm_kernel(const int* __restrict__ rowptr, const int2* __restrict__ ep,
                                                   const unsigned char* __restrict__ egof8,
                                                   unsigned int* __restrict__ sideb, int n){
  int w = (blockIdx.x*256 + threadIdx.x) >> 6;
  int lane = threadIdx.x & 63;
  if (w >= n) return;
  int s = rowptr[w], e = rowptr[w+1];
  float ax = 0.f, ay = 0.f;
  for (int base = s; base < e; base += 16){
    int cnt = e - base;          // >= 1
    int2 E[16]; unsigned short X[16];
    #pragma unroll
    for (int k = 0; k < 16; k++){
      int idx = base + (k < cnt ? k : cnt-1);
      E[k] = ep[idx];
    }
    #pragma unroll
    for (int k = 0; k < 16; k++)
      X[k] = *(const unsigned short*)(egof8 + (size_t)(unsigned)E[k].x + lane*2);
    #pragma unroll
    for (int k = 0; k < 16; k++){
      f32x2 d = __builtin_amdgcn_cvt_pk_f32_fp8((int)X[k], false);
      float v = (k < cnt) ? __int_as_float(E[k].y) : 0.f;
      ax = fmaf(v, d[0], ax); ay = fmaf(v, d[1], ay);
    }
  }
  sideb[(size_t)w*64 + lane] = (unsigned int)f2bf(ax) | ((unsigned int)f2bf(ay) << 16);
}

// MFMA transform: egob[r] = bf16(leaky( [side | ego.*side] @ Wc + b ));
// also writes the fp8 shadow for the next layer's spmm gather.
__global__ __launch_bounds__(256, 4) void transform_kernel(const unsigned int* __restrict__ sideb,
                                                           unsigned int* __restrict__ egob,
                                                           unsigned char* __restrict__ egof8,
                                                           const unsigned short* __restrict__ Wf,
                                                           const float* __restrict__ b1, const float* __restrict__ b2,
                                                           int n){
  __shared__ __align__(16) unsigned short X[64 * XPAD];   // 33 KB
  int row0 = blockIdx.x * 64;
  int tid = threadIdx.x;
  for (int idx = tid; idx < 64*64; idx += 256){
    int r = idx >> 6, cp = idx & 63;
    int row = row0 + r;
    unsigned int sv = 0, pv = 0;
    if (row < n){
      unsigned int s2 = sideb[(size_t)row*64 + cp];
      unsigned int eb = egob[(size_t)row*64 + cp];
      sv = s2;
      pv = (unsigned int)f2bf(bf_lo(s2) * bf_lo(eb)) | ((unsigned int)f2bf(bf_hi(s2) * bf_hi(eb)) << 16);
    }
    *(unsigned int*)&X[r*XPAD + 2*cp]       = sv;
    *(unsigned int*)&X[r*XPAD + 128 + 2*cp] = pv;
  }
  __syncthreads();

  int wave = tid >> 6, lane = tid & 63;
  int wr0 = wave * 16;
  int m = lane & 15, quad = lane >> 4;

  f32x4 acc[8];
  #pragma unroll
  for (int t = 0; t < 8; t++) acc[t] = (f32x4){0.f, 0.f, 0.f, 0.f};

  const unsigned short* arow = &X[(wr0 + m)*XPAD + quad*8];
  #pragma unroll
  for (int ks = 0; ks < 8; ks++){
    bf16x8 a = *(const bf16x8*)(arow + ks*32);
    #pragma unroll
    for (int t = 0; t < 8; t++){
      bf16x8 b = *(const bf16x8*)&Wf[((ks*8 + t)*64 + lane)*8];
      acc[t] = __builtin_amdgcn_mfma_f32_16x16x32_bf16(a, b, acc[t], 0, 0, 0);
    }
  }

  unsigned short* ego16 = (unsigned short*)egob;
  #pragma unroll
  for (int t = 0; t < 8; t++){
    int col = t*16 + m;
    float bb = b1[col] + b2[col];
    #pragma unroll
    for (int r = 0; r < 4; r++){
      int row = row0 + wr0 + quad*4 + r;
      if (row < n){
        float v = acc[t][r] + bb;
        v = v > 0.f ? v : NEG_SLOPE*v;
        ego16[(size_t)row*D + col] = f2bf(v);
        egof8[(size_t)row*D + col] =
            (unsigned char)(__builtin_amdgcn_cvt_pk_fp8_f32(v, v, 0, false) & 0xff);
      }
    }
  }
}

// Per-sample dot contributions of the current block (bf16 base).
__global__ __launch_bounds__(256) void score_kernel(const unsigned int* __restrict__ egob, const int* __restrict__ user,
                                                    const int* __restrict__ pos, const int* __restrict__ neg,
                                                    float* __restrict__ pacc, float* __restrict__ nacc,
                                                    int B, int U, int normalize){
  int w = (blockIdx.x*256 + threadIdx.x) >> 6;
  int lane = threadIdx.x & 63;
  if (w >= B) return;
  size_t ur = (size_t)user[w] * 64;
  size_t pr = ((size_t)U + pos[w]) * 64;
  size_t nr = ((size_t)U + neg[w]) * 64;
  unsigned int ub = egob[ur + lane], pb = egob[pr + lane], nb = egob[nr + lane];
  float ux = bf_lo(ub), uy = bf_hi(ub);
  float px = bf_lo(pb), py = bf_hi(pb);
  float nx = bf_lo(nb), ny = bf_hi(nb);
  float dup = ux*px + uy*py;
  float dun = ux*nx + uy*ny;
  float nu  = ux*ux + uy*uy;
  float np  = px*px + py*py;
  float nn  = nx*nx + ny*ny;
  dup = wave_red(dup); dun = wave_red(dun);
  nu = wave_red(nu); np = wave_red(np); nn = wave_red(nn);
  if (lane == 0){
    if (normalize){
      float inu = 1.f / fmaxf(sqrtf(nu), NORM_EPS);
      float inp = 1.f / fmaxf(sqrtf(np), NORM_EPS);
      float inn = 1.f / fmaxf(sqrtf(nn), NORM_EPS);
      pacc[w] += dup * inu * inp;
      nacc[w] += dun * inu * inn;
    } else {
      pacc[w] += dup;
      nacc[w] += dun;
    }
  }
}

__global__ __launch_bounds__(256) void reg_kernel(const float* __restrict__ item, const int* __restrict__ pos,
                                                  const int* __restrict__ neg, float* __restrict__ reg_out, int B){
  int w = (blockIdx.x*256 + threadIdx.x) >> 6;
  int lane = threadIdx.x & 63;
  if (w >= B) return;
  const float2* it = (const float2*)item;
  float2 pv = it[(size_t)pos[w]*64 + lane];
  float2 nv = it[(size_t)neg[w]*64 + lane];
  float v = pv.x*pv.x + pv.y*pv.y + nv.x*nv.x + nv.y*nv.y;
  v = wave_red(v);
  if (lane == 0) atomicAdd(reg_out, v);
}

__global__ __launch_bounds__(256) void final_kernel(const float* __restrict__ pacc, const float* __restrict__ nacc,
                                                    const float* __restrict__ reg_sum, float* __restrict__ out, int B){
  __shared__ float red[256];
  float s = 0.f;
  for (int i = threadIdx.x; i < B; i += 256){
    float x = nacc[i] - pacc[i];
    s += (x > 0.f) ? x + log1pf(expf(-x)) : log1pf(expf(x));   // softplus, stable
  }
  red[threadIdx.x] = s; __syncthreads();
  for (int o = 128; o > 0; o >>= 1){
    if (threadIdx.x < o) red[threadIdx.x] += red[threadIdx.x + o];
    __syncthreads();
  }
  if (threadIdx.x == 0){
    out[0] = red[0] / (float)B;
    out[1] = REG_LAMBDA * 0.5f * reg_sum[0] / (float)B;
  }
}

extern "C" void kernel_launch(void* const* d_in, const int* in_sizes, int n_in,
                              void* d_out, int out_size, void* d_ws, size_t ws_size,
                              hipStream_t stream) {
  const int*   user = (const int*)d_in[0];
  const int*   pos  = (const int*)d_in[1];
  const int*   neg  = (const int*)d_in[2];
  const int*   erow = (const int*)d_in[3];
  const int*   ecol = (const int*)d_in[4];
  const float* eval = (const float*)d_in[5];
  const float* uemb = (const float*)d_in[6];
  const float* iemb = (const float*)d_in[7];
  const float* Wg   = (const float*)d_in[8];
  const float* bg   = (const float*)d_in[9];
  const float* Wb   = (const float*)d_in[10];
  const float* bb   = (const float*)d_in[11];

  int B   = in_sizes[0];
  int NNZ = in_sizes[3];
  int U   = in_sizes[6] / D;
  int I   = in_sizes[7] / D;
  int N   = U + I;
  int L   = in_sizes[9] / D;
  int nbk = (N + RPB - 1) >> RPB_SHIFT;
  int Tc  = (N + (1 << TCSH) - 1) >> TCSH;

  char* wsp = (char*)d_ws;
  auto alloc = [&](size_t bytes) -> char* {
    char* p = wsp; wsp += (bytes + 255) & ~(size_t)255; return p;
  };
  size_t side_bytes = (size_t)N * D * 2;
  size_t ebuf_bytes = (size_t)NNZ * 8;
  unsigned int*  sideb  = (unsigned int*)alloc(side_bytes > ebuf_bytes ? side_bytes : ebuf_bytes);
  unsigned int*  egob   = (unsigned int*)alloc((size_t)N * D * 2);     // bf16 ego, pair-packed
  unsigned short* egof8 = (unsigned short*)alloc((size_t)N * D);      // fp8-e4m3 ego, pair-packed
  int2*          ep     = (int2*) alloc((size_t)NNZ * 8);              // CSR edges (byte-off, val)
  unsigned short* Wf    = (unsigned short*)alloc((size_t)L * 256 * D * 2);
  int*           rowptr = (int*)  alloc((size_t)(N + 1) * 4);
  int*           bcnt   = (int*)  alloc((size_t)MAXB * 4);
  int*           bbase  = (int*)  alloc((size_t)(MAXB + 1) * 4);
  int*           bcur   = (int*)  alloc((size_t)MAXB * 4);
  float*         pacc   = (float*)alloc((size_t)B * 4);
  float*         nacc   = (float*)alloc((size_t)B * 4);
  float*         regs   = (float*)alloc(256);
  int2*          ebuf   = (int2*)sideb;   // staging alias (build phase only)

  hipMemsetAsync(bcnt, 0, (size_t)nbk * 4, stream);
  hipMemsetAsync(pacc, 0, (size_t)B * 4, stream);
  hipMemsetAsync(nacc, 0, (size_t)B * 4, stream);
  hipMemsetAsync(regs, 0, 4, stream);

  toq_kernel<<<(U*64 + 255) / 256, 256, 0, stream>>>(uemb, egob, egof8, U*64);
  toq_kernel<<<(I*64 + 255) / 256, 256, 0, stream>>>(iemb, egob + (size_t)U*64, egof8 + (size_t)U*64, I*64);
  wconv_kernel<<<(L*256*D + 255) / 256, 256, 0, stream>>>(Wg, Wb, Wf, L);

  // Bucketed CSR build (edges within a row ordered by col-tile)
  bhist_kernel<<<1024, 256, 0, stream>>>(erow, bcnt, NNZ, nbk);
  bscan_kernel<<<1, 1024, 0, stream>>>(bcnt, bbase, bcur, rowptr, nbk, NNZ, N);
  bscatter_kernel<<<(NNZ + CHUNK - 1) / CHUNK, 256, 0, stream>>>(erow, ecol, eval, bcur, ebuf, NNZ, nbk);
  fscatter_kernel<<<nbk, 256, 0, stream>>>(ebuf, bbase, ep, rowptr, Tc, N);

  // Block 0 (raw embeddings, un-normalized)
  score_kernel<<<(B + 3) / 4, 256, 0, stream>>>(egob, user, pos, neg, pacc, nacc, B, U, 0);

  for (int l = 0; l < L; l++){
    spmm_kernel<<<(N + 3) / 4, 256, 0, stream>>>(rowptr, ep, (const unsigned char*)egof8, sideb, N);
    transform_kernel<<<(N + 63) / 64, 256, 0, stream>>>(
        sideb, egob, (unsigned char*)egof8, Wf + (size_t)l * 256 * D,
        bg + (size_t)l * D, bb + (size_t)l * D, N);
    score_kernel<<<(B + 3) / 4, 256, 0, stream>>>(egob, user, pos, neg, pacc, nacc, B, U, 1);
  }

  reg_kernel<<<(B + 3) / 4, 256, 0, stream>>>(iemb, pos, neg, regs, B);
  final_kernel<<<1, 256, 0, stream>>>(pacc, nacc, regs, (float*)d_out, B);
}

// Round 8
// 911.492 us; speedup vs baseline: 1.3846x; 1.3846x over previous
//
#include <hip/hip_runtime.h>
#include <math.h>

#define D 128
#define NEG_SLOPE 0.2f
#define REG_LAMBDA 1e-4f
#define NORM_EPS 1e-12f

#define RPB 256          // rows per coarse bucket
#define RPB_SHIFT 8
#define MAXB 1024        // max coarse buckets (N <= 262144)
#define CHUNK 4096       // edges per bscatter block
#define TCSH 14          // 16384 cols per col-tile (for within-row edge ordering)
#define KEYMAX 4096      // 256 rows * Tc ; Tc<=16 -> N <= 262144

#define XPAD 264         // padded LDS row stride in bf16 elems (256 + 8)

using bf16x8 = __attribute__((ext_vector_type(8))) short;
using f32x4  = __attribute__((ext_vector_type(4))) float;
using f32x2  = __attribute__((ext_vector_type(2))) float;

__device__ __forceinline__ float wave_red(float v){
  #pragma unroll
  for (int o = 32; o > 0; o >>= 1) v += __shfl_xor(v, o, 64);
  return v;
}

__device__ __forceinline__ unsigned short f2bf(float f){
  unsigned int u = __float_as_uint(f);
  unsigned int r = (u + 0x7fffu + ((u >> 16) & 1u)) >> 16;  // RNE
  return (unsigned short)r;
}
__device__ __forceinline__ float bf_lo(unsigned int x){ return __uint_as_float(x << 16); }
__device__ __forceinline__ float bf_hi(unsigned int x){ return __uint_as_float(x & 0xffff0000u); }

// fp32 pair -> (bf16 pair packed in uint, fp8-e4m3 pair packed in ushort)
__global__ __launch_bounds__(256) void toq_kernel(const float* __restrict__ src, unsigned int* __restrict__ dstb,
                                                  unsigned short* __restrict__ dst8, int npairs){
  int i = blockIdx.x*256 + threadIdx.x;
  if (i >= npairs) return;
  float2 v = ((const float2*)src)[i];
  dstb[i] = (unsigned int)f2bf(v.x) | ((unsigned int)f2bf(v.y) << 16);
  int p = __builtin_amdgcn_cvt_pk_fp8_f32(v.x, v.y, 0, false);
  dst8[i] = (unsigned short)(p & 0xffff);
}

// W_gcn/W_bi (fp32 row-major) -> per-layer MFMA B-fragment order bf16.
__global__ __launch_bounds__(256) void wconv_kernel(const float* __restrict__ Wg, const float* __restrict__ Wb,
                                                    unsigned short* __restrict__ Wf, int L){
  int idx = blockIdx.x*256 + threadIdx.x;
  int total = L * 256 * D;
  if (idx >= total) return;
  int l = idx >> 15;
  int rem = idx & 32767;
  int k = rem >> 7;
  int n = rem & 127;
  float v = (k < 128) ? Wg[((size_t)l*128 + k)*D + n] : Wb[((size_t)l*128 + (k-128))*D + n];
  int ks = k >> 5, quad = (k >> 3) & 3, j = k & 7;
  int t = n >> 4, ln = (quad << 4) | (n & 15);
  Wf[(size_t)l*32768 + (((ks*8 + t)*64 + ln)*8 + j)] = f2bf(v);
}

// K1: coarse bucket histogram, LDS-aggregated
__global__ __launch_bounds__(256) void bhist_kernel(const int* __restrict__ erow, int* __restrict__ bcnt, int nnz, int nbk){
  __shared__ int h[MAXB];
  for (int i = threadIdx.x; i < nbk; i += 256) h[i] = 0;
  __syncthreads();
  int stride = gridDim.x * 256;
  for (int e = blockIdx.x*256 + threadIdx.x; e < nnz; e += stride)
    atomicAdd(&h[erow[e] >> RPB_SHIFT], 1);
  __syncthreads();
  for (int i = threadIdx.x; i < nbk; i += 256){
    int c = h[i];
    if (c) atomicAdd(&bcnt[i], c);
  }
}

// K2: exclusive scan of bucket counts (single block)
__global__ __launch_bounds__(1024) void bscan_kernel(const int* __restrict__ bcnt, int* __restrict__ bbase,
                                                     int* __restrict__ bcur, int* __restrict__ rowptr,
                                                     int nbk, int nnz, int n){
  __shared__ int tmp[1024];
  int t = threadIdx.x;
  int v = (t < nbk) ? bcnt[t] : 0;
  tmp[t] = v; __syncthreads();
  #pragma unroll
  for (int off = 1; off < 1024; off <<= 1){
    int a = (t >= off) ? tmp[t-off] : 0; __syncthreads();
    tmp[t] += a; __syncthreads();
  }
  if (t < nbk){ int b = tmp[t] - v; bbase[t] = b; bcur[t] = b; }
  if (t == 0){ bbase[nbk] = nnz; rowptr[n] = nnz; }
}

// K3: coarse scatter. Block sorts a CHUNK of edges by bucket in LDS, reserves
// global ranges, writes coalesced runs. ebuf.x = col | (row_low8 << 20).
__global__ __launch_bounds__(256) void bscatter_kernel(const int* __restrict__ erow, const int* __restrict__ ecol,
                                                       const float* __restrict__ eval, int* __restrict__ bcur,
                                                       int2* __restrict__ ebuf, int nnz, int nbk){
  __shared__ int2 ls[CHUNK];
  __shared__ int gdst[CHUNK];
  __shared__ int h[MAXB];
  __shared__ int hx[MAXB];
  __shared__ int tmp[256];
  int tid = threadIdx.x;
  int base = blockIdx.x * CHUNK;
  int cn = min(CHUNK, nnz - base);
  for (int i = tid; i < nbk; i += 256) h[i] = 0;
  __syncthreads();
  for (int i = tid; i < cn; i += 256)
    atomicAdd(&h[erow[base+i] >> RPB_SHIFT], 1);
  __syncthreads();
  int b0 = tid*4;
  int c0=0,c1=0,c2=0,c3=0;
  if (b0 < nbk){
    c0 = h[b0];
    if (b0+1 < nbk) c1 = h[b0+1];
    if (b0+2 < nbk) c2 = h[b0+2];
    if (b0+3 < nbk) c3 = h[b0+3];
  }
  int tsum = c0+c1+c2+c3;
  tmp[tid] = tsum; __syncthreads();
  #pragma unroll
  for (int off = 1; off < 256; off <<= 1){
    int a = (tid >= off) ? tmp[tid-off] : 0; __syncthreads();
    tmp[tid] += a; __syncthreads();
  }
  int tbase = tmp[tid] - tsum;
  if (b0 < nbk){
    hx[b0] = tbase;
    if (b0+1 < nbk) hx[b0+1] = tbase + c0;
    if (b0+2 < nbk) hx[b0+2] = tbase + c0 + c1;
    if (b0+3 < nbk) hx[b0+3] = tbase + c0 + c1 + c2;
  }
  __syncthreads();
  for (int i = tid; i < nbk; i += 256){
    int c = h[i];
    if (c > 0){
      int gb = atomicAdd(&bcur[i], c);
      h[i] = gb - hx[i];
    }
  }
  __syncthreads();
  for (int i = tid; i < cn; i += 256){
    int r = erow[base+i];
    int b = r >> RPB_SHIFT;
    int x = ecol[base+i] | ((r & (RPB-1)) << 20);
    int lpos = atomicAdd(&hx[b], 1);
    ls[lpos] = make_int2(x, __float_as_int(eval[base+i]));
    gdst[lpos] = h[b] + lpos;
  }
  __syncthreads();
  for (int i = tid; i < cn; i += 256)
    ebuf[gdst[i]] = ls[i];
}

// K4: one block per coarse bucket. Counting sort by key = (row_low8, col-tile)
// -> rowptr + final CSR (edges within a row ordered by col-tile).
// ep.x = byte offset into fp8 table (col * 128).
__global__ __launch_bounds__(256) void fscatter_kernel(const int2* __restrict__ ebuf, const int* __restrict__ bbase,
                                                       int2* __restrict__ ep, int* __restrict__ rowptr,
                                                       int Tc, int n){
  __shared__ int h[KEYMAX];
  __shared__ int tsum[256];
  int b = blockIdx.x;
  int tid = threadIdx.x;
  int s = bbase[b], e = bbase[b+1];
  int row0 = b << RPB_SHIFT;
  int nk = 256 * Tc;
  for (int i = tid; i < nk; i += 256) h[i] = 0;
  __syncthreads();
  for (int i = s + tid; i < e; i += 256){
    int x = ebuf[i].x;
    int key = ((x >> 20) & 255) * Tc + ((x & 0xFFFFF) >> TCSH);
    atomicAdd(&h[key], 1);
  }
  __syncthreads();
  // exclusive scan: thread tid owns keys of row tid (segment of Tc)
  int my0 = tid * Tc;
  int run = 0;
  for (int j = 0; j < Tc; j++){
    int c = h[my0 + j]; h[my0 + j] = run; run += c;
  }
  tsum[tid] = run; __syncthreads();
  #pragma unroll
  for (int off = 1; off < 256; off <<= 1){
    int a = (tid >= off) ? tsum[tid-off] : 0; __syncthreads();
    tsum[tid] += a; __syncthreads();
  }
  int bt = tsum[tid] - run;
  for (int j = 0; j < Tc; j++) h[my0 + j] += bt;
  __syncthreads();
  if (row0 + tid < n) rowptr[row0 + tid] = s + h[my0];
  __syncthreads();
  for (int i = s + tid; i < e; i += 256){
    int2 E = ebuf[i];
    int x = E.x;
    int col = x & 0xFFFFF;
    int key = ((x >> 20) & 255) * Tc + (col >> TCSH);
    int p = atomicAdd(&h[key], 1);
    ep[s + p] = make_int2(col << 7, E.y);   // byte offset
  }
}

// sideb[r] = bf16( sum_e val_e * ego_fp8[off_e] ); one wave per row.
// 4 edges per gather instruction: lane i reads 8 B of row E[i>>4] at byte
// (i&15)*8 -> 64 lanes span 4 random lines (512 B) per VMEM instr, 4x the
// outstanding-line MLP of a 1-line gather. Per-lane acc covers 8 columns;
// shfl_xor(16/32) folds the 4 lane-groups; lanes 0-15 store the row.
__global__ __launch_bounds__(256) void spmm_kernel(const int* __restrict__ rowptr, const int2* __restrict__ ep,
                                                   const unsigned char* __restrict__ egof8,
                                                   unsigned int* __restrict__ sideb, int n){
  int w = (blockIdx.x*256 + threadIdx.x) >> 6;
  int lane = threadIdx.x & 63;
  if (w >= n) return;
  int s = rowptr[w], e = rowptr[w+1];
  int sub  = lane >> 4;     // which edge of the quad
  int half = lane & 15;     // which 8-byte segment of the 128-B row
  float acc[8];
  #pragma unroll
  for (int j = 0; j < 8; j++) acc[j] = 0.f;
  for (int base = s; base < e; base += 16){
    int2 E[4]; uint2 X[4];
    #pragma unroll
    for (int k = 0; k < 4; k++){
      int idx = base + 4*k + sub;
      idx = idx < e ? idx : e - 1;
      E[k] = ep[idx];
    }
    #pragma unroll
    for (int k = 0; k < 4; k++)
      X[k] = *(const uint2*)(egof8 + (size_t)(unsigned)E[k].x + half*8);
    #pragma unroll
    for (int k = 0; k < 4; k++){
      float v = (base + 4*k + sub < e) ? __int_as_float(E[k].y) : 0.f;
      f32x2 d0 = __builtin_amdgcn_cvt_pk_f32_fp8((int)X[k].x, false);
      f32x2 d1 = __builtin_amdgcn_cvt_pk_f32_fp8((int)X[k].x, true);
      f32x2 d2 = __builtin_amdgcn_cvt_pk_f32_fp8((int)X[k].y, false);
      f32x2 d3 = __builtin_amdgcn_cvt_pk_f32_fp8((int)X[k].y, true);
      acc[0] = fmaf(v, d0[0], acc[0]); acc[1] = fmaf(v, d0[1], acc[1]);
      acc[2] = fmaf(v, d1[0], acc[2]); acc[3] = fmaf(v, d1[1], acc[3]);
      acc[4] = fmaf(v, d2[0], acc[4]); acc[5] = fmaf(v, d2[1], acc[5]);
      acc[6] = fmaf(v, d3[0], acc[6]); acc[7] = fmaf(v, d3[1], acc[7]);
    }
  }
  #pragma unroll
  for (int j = 0; j < 8; j++){
    acc[j] += __shfl_xor(acc[j], 16, 64);
    acc[j] += __shfl_xor(acc[j], 32, 64);
  }
  if (lane < 16){
    unsigned int o0 = (unsigned int)f2bf(acc[0]) | ((unsigned int)f2bf(acc[1]) << 16);
    unsigned int o1 = (unsigned int)f2bf(acc[2]) | ((unsigned int)f2bf(acc[3]) << 16);
    unsigned int o2 = (unsigned int)f2bf(acc[4]) | ((unsigned int)f2bf(acc[5]) << 16);
    unsigned int o3 = (unsigned int)f2bf(acc[6]) | ((unsigned int)f2bf(acc[7]) << 16);
    *(uint4*)(sideb + (size_t)w*64 + half*4) = make_uint4(o0, o1, o2, o3);
  }
}

// MFMA transform: egob[r] = bf16(leaky( [side | ego.*side] @ Wc + b ));
// also writes the fp8 shadow for the next layer's spmm gather.
__global__ __launch_bounds__(256, 4) void transform_kernel(const unsigned int* __restrict__ sideb,
                                                           unsigned int* __restrict__ egob,
                                                           unsigned char* __restrict__ egof8,
                                                           const unsigned short* __restrict__ Wf,
                                                           const float* __restrict__ b1, const float* __restrict__ b2,
                                                           int n){
  __shared__ __align__(16) unsigned short X[64 * XPAD];   // 33 KB
  int row0 = blockIdx.x * 64;
  int tid = threadIdx.x;
  for (int idx = tid; idx < 64*64; idx += 256){
    int r = idx >> 6, cp = idx & 63;
    int row = row0 + r;
    unsigned int sv = 0, pv = 0;
    if (row < n){
      unsigned int s2 = sideb[(size_t)row*64 + cp];
      unsigned int eb = egob[(size_t)row*64 + cp];
      sv = s2;
      pv = (unsigned int)f2bf(bf_lo(s2) * bf_lo(eb)) | ((unsigned int)f2bf(bf_hi(s2) * bf_hi(eb)) << 16);
    }
    *(unsigned int*)&X[r*XPAD + 2*cp]       = sv;
    *(unsigned int*)&X[r*XPAD + 128 + 2*cp] = pv;
  }
  __syncthreads();

  int wave = tid >> 6, lane = tid & 63;
  int wr0 = wave * 16;
  int m = lane & 15, quad = lane >> 4;

  f32x4 acc[8];
  #pragma unroll
  for (int t = 0; t < 8; t++) acc[t] = (f32x4){0.f, 0.f, 0.f, 0.f};

  const unsigned short* arow = &X[(wr0 + m)*XPAD + quad*8];
  #pragma unroll
  for (int ks = 0; ks < 8; ks++){
    bf16x8 a = *(const bf16x8*)(arow + ks*32);
    #pragma unroll
    for (int t = 0; t < 8; t++){
      bf16x8 b = *(const bf16x8*)&Wf[((ks*8 + t)*64 + lane)*8];
      acc[t] = __builtin_amdgcn_mfma_f32_16x16x32_bf16(a, b, acc[t], 0, 0, 0);
    }
  }

  unsigned short* ego16 = (unsigned short*)egob;
  #pragma unroll
  for (int t = 0; t < 8; t++){
    int col = t*16 + m;
    float bb = b1[col] + b2[col];
    #pragma unroll
    for (int r = 0; r < 4; r++){
      int row = row0 + wr0 + quad*4 + r;
      if (row < n){
        float v = acc[t][r] + bb;
        v = v > 0.f ? v : NEG_SLOPE*v;
        ego16[(size_t)row*D + col] = f2bf(v);
        egof8[(size_t)row*D + col] =
            (unsigned char)(__builtin_amdgcn_cvt_pk_fp8_f32(v, v, 0, false) & 0xff);
      }
    }
  }
}

// Per-sample dot contributions of the current block (bf16 base).
__global__ __launch_bounds__(256) void score_kernel(const unsigned int* __restrict__ egob, const int* __restrict__ user,
                                                    const int* __restrict__ pos, const int* __restrict__ neg,
                                                    float* __restrict__ pacc, float* __restrict__ nacc,
                                                    int B, int U, int normalize){
  int w = (blockIdx.x*256 + threadIdx.x) >> 6;
  int lane = threadIdx.x & 63;
  if (w >= B) return;
  size_t ur = (size_t)user[w] * 64;
  size_t pr = ((size_t)U + pos[w]) * 64;
  size_t nr = ((size_t)U + neg[w]) * 64;
  unsigned int ub = egob[ur + lane], pb = egob[pr + lane], nb = egob[nr + lane];
  float ux = bf_lo(ub), uy = bf_hi(ub);
  float px = bf_lo(pb), py = bf_hi(pb);
  float nx = bf_lo(nb), ny = bf_hi(nb);
  float dup = ux*px + uy*py;
  float dun = ux*nx + uy*ny;
  float nu  = ux*ux + uy*uy;
  float np  = px*px + py*py;
  float nn  = nx*nx + ny*ny;
  dup = wave_red(dup); dun = wave_red(dun);
  nu = wave_red(nu); np = wave_red(np); nn = wave_red(nn);
  if (lane == 0){
    if (normalize){
      float inu = 1.f / fmaxf(sqrtf(nu), NORM_EPS);
      float inp = 1.f / fmaxf(sqrtf(np), NORM_EPS);
      float inn = 1.f / fmaxf(sqrtf(nn), NORM_EPS);
      pacc[w] += dup * inu * inp;
      nacc[w] += dun * inu * inn;
    } else {
      pacc[w] += dup;
      nacc[w] += dun;
    }
  }
}

__global__ __launch_bounds__(256) void reg_kernel(const float* __restrict__ item, const int* __restrict__ pos,
                                                  const int* __restrict__ neg, float* __restrict__ reg_out, int B){
  int w = (blockIdx.x*256 + threadIdx.x) >> 6;
  int lane = threadIdx.x & 63;
  if (w >= B) return;
  const float2* it = (const float2*)item;
  float2 pv = it[(size_t)pos[w]*64 + lane];
  float2 nv = it[(size_t)neg[w]*64 + lane];
  float v = pv.x*pv.x + pv.y*pv.y + nv.x*nv.x + nv.y*nv.y;
  v = wave_red(v);
  if (lane == 0) atomicAdd(reg_out, v);
}

__global__ __launch_bounds__(256) void final_kernel(const float* __restrict__ pacc, const float* __restrict__ nacc,
                                                    const float* __restrict__ reg_sum, float* __restrict__ out, int B){
  __shared__ float red[256];
  float s = 0.f;
  for (int i = threadIdx.x; i < B; i += 256){
    float x = nacc[i] - pacc[i];
    s += (x > 0.f) ? x + log1pf(expf(-x)) : log1pf(expf(x));   // softplus, stable
  }
  red[threadIdx.x] = s; __syncthreads();
  for (int o = 128; o > 0; o >>= 1){
    if (threadIdx.x < o) red[threadIdx.x] += red[threadIdx.x + o];
    __syncthreads();
  }
  if (threadIdx.x == 0){
    out[0] = red[0] / (float)B;
    out[1] = REG_LAMBDA * 0.5f * reg_sum[0] / (float)B;
  }
}

extern "C" void kernel_launch(void* const* d_in, const int* in_sizes, int n_in,
                              void* d_out, int out_size, void* d_ws, size_t ws_size,
                              hipStream_t stream) {
  const int*   user = (const int*)d_in[0];
  const int*   pos  = (const int*)d_in[1];
  const int*   neg  = (const int*)d_in[2];
  const int*   erow = (const int*)d_in[3];
  const int*   ecol = (const int*)d_in[4];
  const float* eval = (const float*)d_in[5];
  const float* uemb = (const float*)d_in[6];
  const float* iemb = (const float*)d_in[7];
  const float* Wg   = (const float*)d_in[8];
  const float* bg   = (const float*)d_in[9];
  const float* Wb   = (const float*)d_in[10];
  const float* bb   = (const float*)d_in[11];

  int B   = in_sizes[0];
  int NNZ = in_sizes[3];
  int U   = in_sizes[6] / D;
  int I   = in_sizes[7] / D;
  int N   = U + I;
  int L   = in_sizes[9] / D;
  int nbk = (N + RPB - 1) >> RPB_SHIFT;
  int Tc  = (N + (1 << TCSH) - 1) >> TCSH;

  char* wsp = (char*)d_ws;
  auto alloc = [&](size_t bytes) -> char* {
    char* p = wsp; wsp += (bytes + 255) & ~(size_t)255; return p;
  };
  size_t side_bytes = (size_t)N * D * 2;
  size_t ebuf_bytes = (size_t)NNZ * 8;
  unsigned int*  sideb  = (unsigned int*)alloc(side_bytes > ebuf_bytes ? side_bytes : ebuf_bytes);
  unsigned int*  egob   = (unsigned int*)alloc((size_t)N * D * 2);     // bf16 ego, pair-packed
  unsigned short* egof8 = (unsigned short*)alloc((size_t)N * D);      // fp8-e4m3 ego, pair-packed
  int2*          ep     = (int2*) alloc((size_t)NNZ * 8);              // CSR edges (byte-off, val)
  unsigned short* Wf    = (unsigned short*)alloc((size_t)L * 256 * D * 2);
  int*           rowptr = (int*)  alloc((size_t)(N + 1) * 4);
  int*           bcnt   = (int*)  alloc((size_t)MAXB * 4);
  int*           bbase  = (int*)  alloc((size_t)(MAXB + 1) * 4);
  int*           bcur   = (int*)  alloc((size_t)MAXB * 4);
  float*         pacc   = (float*)alloc((size_t)B * 4);
  float*         nacc   = (float*)alloc((size_t)B * 4);
  float*         regs   = (float*)alloc(256);
  int2*          ebuf   = (int2*)sideb;   // staging alias (build phase only)

  hipMemsetAsync(bcnt, 0, (size_t)nbk * 4, stream);
  hipMemsetAsync(pacc, 0, (size_t)B * 4, stream);
  hipMemsetAsync(nacc, 0, (size_t)B * 4, stream);
  hipMemsetAsync(regs, 0, 4, stream);

  toq_kernel<<<(U*64 + 255) / 256, 256, 0, stream>>>(uemb, egob, egof8, U*64);
  toq_kernel<<<(I*64 + 255) / 256, 256, 0, stream>>>(iemb, egob + (size_t)U*64, egof8 + (size_t)U*64, I*64);
  wconv_kernel<<<(L*256*D + 255) / 256, 256, 0, stream>>>(Wg, Wb, Wf, L);

  // Bucketed CSR build (edges within a row ordered by col-tile)
  bhist_kernel<<<2048, 256, 0, stream>>>(erow, bcnt, NNZ, nbk);
  bscan_kernel<<<1, 1024, 0, stream>>>(bcnt, bbase, bcur, rowptr, nbk, NNZ, N);
  bscatter_kernel<<<(NNZ + CHUNK - 1) / CHUNK, 256, 0, stream>>>(erow, ecol, eval, bcur, ebuf, NNZ, nbk);
  fscatter_kernel<<<nbk, 256, 0, stream>>>(ebuf, bbase, ep, rowptr, Tc, N);

  // Block 0 (raw embeddings, un-normalized)
  score_kernel<<<(B + 3) / 4, 256, 0, stream>>>(egob, user, pos, neg, pacc, nacc, B, U, 0);

  for (int l = 0; l < L; l++){
    spmm_kernel<<<(N + 3) / 4, 256, 0, stream>>>(rowptr, ep, (const unsigned char*)egof8, sideb, N);
    transform_kernel<<<(N + 63) / 64, 256, 0, stream>>>(
        sideb, egob, (unsigned char*)egof8, Wf + (size_t)l * 256 * D,
        bg + (size_t)l * D, bb + (size_t)l * D, N);
    score_kernel<<<(B + 3) / 4, 256, 0, stream>>>(egob, user, pos, neg, pacc, nacc, B, U, 1);
  }

  reg_kernel<<<(B + 3) / 4, 256, 0, stream>>>(iemb, pos, neg, regs, B);
  final_kernel<<<1, 256, 0, stream>>>(pacc, nacc, regs, (float*)d_out, B);
}